// Round 1
// 277.654 us; speedup vs baseline: 1.0482x; 1.0482x over previous
//
#include <hip/hip_runtime.h>
#include <hip/hip_bf16.h>

#define H 128
#define NT 4
#define CAP4 40
#define BK 64

typedef __attribute__((ext_vector_type(8))) _Float16 half8;
typedef __attribute__((ext_vector_type(4))) float f32x4;

#if defined(__has_builtin)
#if __has_builtin(__builtin_amdgcn_global_load_lds)
#define HAS_GLL 1
#endif
#endif
#ifndef HAS_GLL
#define HAS_GLL 0
#endif

__device__ __forceinline__ float bf2f(unsigned short u) {
    union { unsigned int i; float f; } v;
    v.i = ((unsigned int)u) << 16;
    return v.f;
}

__device__ __forceinline__ unsigned short f2bf(float f) {
    union { float f; unsigned int i; } v;
    v.f = f;
    unsigned int x = v.i;
    unsigned int r = (x + 0x7fffu + ((x >> 16) & 1u)) >> 16;  // RNE
    return (unsigned short)r;
}

__device__ __forceinline__ float fsigmoid(float x) {
    return 1.0f / (1.0f + __expf(-x));
}
__device__ __forceinline__ float ftanh(float x) {
    return 1.0f - 2.0f / (__expf(2.0f * x) + 1.0f);  // inf-safe both tails
}

// flag-adaptive fp32 read from raw input buffer (1 = bf16-packed, 0 = fp32)
__device__ __forceinline__ float readf(const void* p, long i, int isbf) {
    return isbf ? bf2f(((const unsigned short*)p)[i]) : ((const float*)p)[i];
}

// ---------------------------------------------------------------------------
// async global->LDS 16B
// ---------------------------------------------------------------------------
__device__ __forceinline__ void gll16(const _Float16* g, _Float16* l) {
#if HAS_GLL
    __builtin_amdgcn_global_load_lds(
        (const __attribute__((address_space(1))) unsigned int*)g,
        (__attribute__((address_space(3))) unsigned int*)l, 16, 0, 0);
#endif
}

// ---------------------------------------------------------------------------
// Stage a (RPW*4)row x 64k fp16 tile into LDS, unpadded (row stride 64 halfs),
// XOR-swizzled: LDS[r][chunk p] holds global chunk (p ^ (r&7)).
// RPW = rows per wave (16 -> 64-row tile, 32 -> 128-row tile).
// ---------------------------------------------------------------------------
template<int RPW>
__device__ __forceinline__ void stage_tileT(
    const _Float16* __restrict__ gbase, int rstride, int row0, int kof,
    int maxrow, _Float16* lds) {
    const int wave = threadIdx.x >> 6, lane = threadIdx.x & 63;
#pragma unroll
    for (int s = 0; s < RPW / 8; s++) {
        int R = wave * RPW + s * 8;               // 8-row group (8-aligned)
        int rl = R + (lane >> 3);
        int rg = row0 + rl;
        if (rg >= maxrow) rg = maxrow - 1;
        int chunk = (lane & 7) ^ (rl & 7);
        const _Float16* gp = gbase + (size_t)rg * rstride + kof + chunk * 8;
#if HAS_GLL
        gll16(gp, lds + R * 64);
#else
        *(half8*)&lds[rl * 64 + (lane & 7) * 8] = *(const half8*)gp;
#endif
    }
}

// fragment read honoring the swizzle: global chunk g (=ks*4+quad) of row r
__device__ __forceinline__ half8 frag(const _Float16* lds, int r, int g) {
    return *(const half8*)&lds[r * 64 + ((g ^ (r & 7)) * 8)];
}

// ---------------------------------------------------------------------------
// dtype detector: low u16 of each dword as bf16 exponent sanity test.
// ---------------------------------------------------------------------------
__global__ void detect_dtype(const unsigned short* __restrict__ states_u16,
                             int* __restrict__ flag) {
    __shared__ int cnt;
    if (threadIdx.x == 0) cnt = 0;
    __syncthreads();
    int local = 0;
    for (int i = threadIdx.x; i < 1024; i += 256) {
        unsigned short u = states_u16[2 * i];
        int e = (u >> 7) & 0xFF;
        if (e >= 96 && e <= 158) local++;
    }
    atomicAdd(&cnt, local);
    __syncthreads();
    if (threadIdx.x == 0) *flag = (cnt >= 512) ? 1 : 0;
}

// ---------------------------------------------------------------------------
// prep_all: single consolidated prep kernel (one launch replaces 5):
//   seg 0: states -> h16 (fp16)
//   seg 1: type_W [L][t][k][c] -> BTw [L][c:128][t*128+k:512]
//   seg 2: gru kernels -> BTg2 [L][nc:512][k:256] gate-interleaved
//   seg 3: zero counts4
//   seg 4: biases -> btab/gbsum/gb0c/gb1c
// ---------------------------------------------------------------------------
__global__ void prep_all(
    const void* __restrict__ states, const void* __restrict__ type_W,
    const void* __restrict__ type_b, const void* __restrict__ gk,
    const void* __restrict__ gr, const void* __restrict__ grub,
    _Float16* __restrict__ h16, _Float16* __restrict__ BTw,
    _Float16* __restrict__ BTg, float* __restrict__ btab,
    float* __restrict__ gbsum, float* __restrict__ gb0c,
    float* __restrict__ gb1c, int* __restrict__ counts4,
    const int* __restrict__ flag,
    long NNH, int nBTw, int nBTg, int NC4, int LAYERS) {
    long i = (long)blockIdx.x * 256 + threadIdx.x;
    const int fl = *flag;
    if (i < NNH) {                                  // seg 0
        h16[i] = (_Float16)readf(states, i, fl);
        return;
    }
    i -= NNH;
    if (i < nBTw) {                                 // seg 1
        int l = (int)(i >> 16);
        int rem = (int)(i & 65535);
        int c = rem >> 9, kk = rem & 511;
        int t = kk >> 7, k = kk & 127;
        BTw[i] = (_Float16)readf(type_W, (((long)(l * NT + t) * H) + k) * H + c, fl);
        return;
    }
    i -= nBTw;
    if (i < nBTg) {                                 // seg 2
        int l = (int)(i >> 17);
        int rem = (int)(i & 131071);
        int nc = rem >> 8, k = rem & 255;
        int g = nc >> 6, gate = (nc >> 4) & 3, m = nc & 15;
        int c = g * 16 + m;
        float v = 0.0f;
        if (gate == 0) {
            v = (k < 128) ? readf(gk, ((long)l * H + k) * 384 + c, fl)
                          : readf(gr, ((long)l * H + (k - 128)) * 384 + c, fl);
        } else if (gate == 1) {
            v = (k < 128) ? readf(gk, ((long)l * H + k) * 384 + 128 + c, fl)
                          : readf(gr, ((long)l * H + (k - 128)) * 384 + 128 + c, fl);
        } else if (gate == 2) {
            if (k < 128) v = readf(gk, ((long)l * H + k) * 384 + 256 + c, fl);
        } else {
            if (k >= 128) v = readf(gr, ((long)l * H + (k - 128)) * 384 + 256 + c, fl);
        }
        BTg[i] = (_Float16)v;
        return;
    }
    i -= nBTg;
    if (i < NC4) {                                  // seg 3
        counts4[i] = 0;
        return;
    }
    i -= NC4;
    {                                               // seg 4 (i < LAYERS*NT*H)
        int j = (int)i;
        if (j < LAYERS * NT * H) btab[j] = readf(type_b, j, fl);
        if (j < LAYERS * 256) {
            int l = j >> 8, c = j & 255;
            gbsum[j] = readf(grub, (long)l * 768 + c, fl) +
                       readf(grub, (long)l * 768 + 384 + c, fl);
        }
        if (j < LAYERS * H) {
            int l = j >> 7, c = j & 127;
            gb0c[j] = readf(grub, (long)l * 768 + 256 + c, fl);
            gb1c[j] = readf(grub, (long)l * 768 + 384 + 256 + c, fl);
        }
    }
}

// ---------------------------------------------------------------------------
// bucket edges by (dst, type); counts4 zeroed by prep_all. counts4[NN][4]
// doubles as the int4 per-row count table for the fused bias epilogue.
// ---------------------------------------------------------------------------
__global__ void place_edges4(const int* __restrict__ edges, int* __restrict__ counts4,
                             int* __restrict__ buckets4, int NE) {
    int e = blockIdx.x * 256 + threadIdx.x;
    if (e >= NE) return;
    int t = edges[3 * e], src = edges[3 * e + 1], dst = edges[3 * e + 2];
    int slot = atomicAdd(&counts4[dst * 4 + t], 1);
    if (slot < CAP4) buckets4[((size_t)dst * 4 + t) * CAP4 + slot] = src;
}

// ---------------------------------------------------------------------------
// gather4: one wave per node; quarter-wave q owns type-q's edge list.
// Lane i of group q reads h16[src][i*8 .. i*8+8) (16 lanes x 16B = one row).
// ---------------------------------------------------------------------------
__global__ __launch_bounds__(256) void gather4(
    const _Float16* __restrict__ h16, const int* __restrict__ counts4,
    const int* __restrict__ buckets4, _Float16* __restrict__ A4, int NN) {
    int node = blockIdx.x * 4 + (threadIdx.x >> 6);
    int lane = threadIdx.x & 63;
    int q = lane >> 4, i = lane & 15;
    if (node >= NN) return;
    int cnt = counts4[node * 4 + q];
    if (cnt > CAP4) cnt = CAP4;
    const int* bkt = buckets4 + ((size_t)node * 4 + q) * CAP4;

    float acc[8] = {};
    int e = 0;
    for (; e + 2 <= cnt; e += 2) {
        int s0 = bkt[e], s1 = bkt[e + 1];
        half8 v0 = *(const half8*)&h16[(size_t)s0 * H + i * 8];
        half8 v1 = *(const half8*)&h16[(size_t)s1 * H + i * 8];
#pragma unroll
        for (int j = 0; j < 8; j++) acc[j] += (float)v0[j] + (float)v1[j];
    }
    if (e < cnt) {
        int s0 = bkt[e];
        half8 v0 = *(const half8*)&h16[(size_t)s0 * H + i * 8];
#pragma unroll
        for (int j = 0; j < 8; j++) acc[j] += (float)v0[j];
    }

    half8 o;
#pragma unroll
    for (int j = 0; j < 8; j++) o[j] = (_Float16)acc[j];
    *(half8*)&A4[((size_t)node * 4 + q) * H + i * 8] = o;
}

// ---------------------------------------------------------------------------
// layer_fused: per 64-row tile, does BOTH GEMMs of a layer in one kernel.
//   Phase 1: agg = A4[64r][512] @ BTw[128c][512]^T + cnt-weighted bias,
//            deposited as fp16 in LDS (two 64x64 swizzled tiles) --
//            bit-identical values to the old global agg16 path.
//   Phase 2: loop y=0..3 gate-col groups: C = [agg|h] (K=256) @ BTg_y,
//            zero-K gate skip (gate2 only K<128, gate3 only K>=128),
//            GRU gate epilogue, write hnext (+ final output).
// Eliminates agg16 global round-trip, 4x A-restage, 1 launch/layer.
// LDS = 24KB scratch + 16KB aggL = 40KB -> 4 blocks/CU.
// ---------------------------------------------------------------------------
__global__ __launch_bounds__(256, 4) void layer_fused(
    const _Float16* __restrict__ A4,     // [NN][512]
    const _Float16* __restrict__ h16,    // [NN][128]
    const _Float16* __restrict__ BTw,    // [128c][512k]
    const _Float16* __restrict__ BTg,    // [512nc][256k]
    const float* __restrict__ btab,      // [512]
    const int4* __restrict__ cnt4,       // [NN]
    const float* __restrict__ gbsum,     // [256]
    const float* __restrict__ gb0c,      // [128]
    const float* __restrict__ gb1c,      // [128]
    _Float16* __restrict__ hnext,        // [NN][128]
    void* __restrict__ outbuf,           // final output or nullptr
    const int* __restrict__ flag, int NN) {
    // scratch: phase1 As@0 (4096 halfs) + Bs@4096 (8192 halfs)
    //          phase2 Bs@0 (8192 halfs) + hA@8192 (4096 halfs)
    __shared__ _Float16 scratch[12288];
    __shared__ _Float16 aggL[8192];      // two 64x64 swizzled fp16 tiles

    const int row0 = blockIdx.x * 64;
    const int tid = threadIdx.x;
    const int wave = tid >> 6, lane = tid & 63;
    const int m = lane & 15, quad = lane >> 4;
    const int wr = (wave & 1) * 32, wc = (wave >> 1) * 64;

    f32x4 acc[2][4] = {};

    // ---------------- phase 1: agg GEMM (K=512) ----------------
    for (int kc = 0; kc < 8; kc++) {
        const int k0 = kc * BK;
        __syncthreads();
        stage_tileT<16>(A4, 512, row0, k0, NN, scratch);          // As 64x64
        stage_tileT<32>(BTw, 512, 0, k0, 128, scratch + 4096);    // Bs 128x64
        __syncthreads();
#pragma unroll
        for (int ks = 0; ks < 2; ks++) {
            half8 a[2], b[4];
#pragma unroll
            for (int mt = 0; mt < 2; mt++)
                a[mt] = frag(scratch, wr + mt * 16 + m, ks * 4 + quad);
#pragma unroll
            for (int nt = 0; nt < 4; nt++)
                b[nt] = frag(scratch + 4096, wc + nt * 16 + m, ks * 4 + quad);
#pragma unroll
            for (int mt = 0; mt < 2; mt++)
#pragma unroll
                for (int nt = 0; nt < 4; nt++)
                    acc[mt][nt] = __builtin_amdgcn_mfma_f32_16x16x32_f16(
                        a[mt], b[nt], acc[mt][nt], 0, 0, 0);
        }
    }

    // phase-1 epilogue: +bias, fp16, deposit into aggL (frag-compatible
    // layout: LDS[r][chunk p] = global chunk p^(r&7)).
#pragma unroll
    for (int mt = 0; mt < 2; mt++) {
#pragma unroll
        for (int i = 0; i < 4; i++) {
            int rl = wr + mt * 16 + quad * 4 + i;
            int rg = row0 + rl;
            if (rg >= NN) rg = NN - 1;
            int4 c4 = cnt4[rg];
#pragma unroll
            for (int nt = 0; nt < 4; nt++) {
                int c = wc + nt * 16 + m;
                float bias = c4.x * btab[c] + c4.y * btab[128 + c] +
                             c4.z * btab[256 + c] + c4.w * btab[384 + c];
                int tile = c >> 6, cc = c & 63, g = cc >> 3;
                aggL[tile * 4096 + rl * 64 + ((g ^ (rl & 7)) * 8) + (cc & 7)] =
                    (_Float16)(acc[mt][nt][i] + bias);
            }
        }
    }
    // next __syncthreads() (top of phase-2 kc loop) orders aggL writes
    // before any cross-wave read.

    // ---------------- phase 2: GRU GEMM + gates, per col group ----------------
    const int fl = outbuf ? *flag : 0;
    for (int y = 0; y < 4; y++) {
#pragma unroll
        for (int mt = 0; mt < 2; mt++)
#pragma unroll
            for (int nt = 0; nt < 4; nt++)
                acc[mt][nt] = (f32x4){0.f, 0.f, 0.f, 0.f};

        for (int kc = 0; kc < 4; kc++) {
            const int ntA = (kc < 2) ? 2 : 3;   // zero-K skip: 3rd active gate
            __syncthreads();
            stage_tileT<32>(BTg, 256, y * 128, kc * BK, 512, scratch);  // Bs
            if (kc >= 2)
                stage_tileT<16>(h16, H, row0, (kc - 2) * BK, NN, scratch + 8192);
            __syncthreads();
#pragma unroll
            for (int ks = 0; ks < 2; ks++) {
                const _Float16* Asrc =
                    (kc < 2) ? (aggL + kc * 4096) : (scratch + 8192);
                half8 a[2], b3[3];
#pragma unroll
                for (int mt = 0; mt < 2; mt++)
                    a[mt] = frag(Asrc, wr + mt * 16 + m, ks * 4 + quad);
                b3[0] = frag(scratch, wc + 0 * 16 + m, ks * 4 + quad);
                b3[1] = frag(scratch, wc + 1 * 16 + m, ks * 4 + quad);
                b3[2] = frag(scratch, wc + ntA * 16 + m, ks * 4 + quad);
#pragma unroll
                for (int mt = 0; mt < 2; mt++) {
                    acc[mt][0] = __builtin_amdgcn_mfma_f32_16x16x32_f16(
                        a[mt], b3[0], acc[mt][0], 0, 0, 0);
                    acc[mt][1] = __builtin_amdgcn_mfma_f32_16x16x32_f16(
                        a[mt], b3[1], acc[mt][1], 0, 0, 0);
                    acc[mt][ntA] = __builtin_amdgcn_mfma_f32_16x16x32_f16(
                        a[mt], b3[2], acc[mt][ntA], 0, 0, 0);
                }
            }
        }

        // gate epilogue for this y: h-cols [32y, 32y+32)
        const int g8 = y * 2 + (wc >> 6);
        const int c = g8 * 16 + m;
        const float bz = gbsum[c];
        const float br = gbsum[128 + c];
        const float bx = gb0c[c];
        const float bh = gb1c[c];
#pragma unroll
        for (int mt = 0; mt < 2; mt++) {
#pragma unroll
            for (int i = 0; i < 4; i++) {
                int rl = wr + mt * 16 + quad * 4 + i;
                int row = row0 + rl;
                if (row >= NN) continue;
                float z = fsigmoid(acc[mt][0][i] + bz);
                float r = fsigmoid(acc[mt][1][i] + br);
                float ccand =
                    ftanh((acc[mt][2][i] + bx) + r * (acc[mt][3][i] + bh));
                float hv = (float)h16[(size_t)row * H + c];
                float hn = z * hv + (1.0f - z) * ccand;
                size_t oi = (size_t)row * H + c;
                hnext[oi] = (_Float16)hn;
                if (outbuf) {
                    if (fl) ((unsigned short*)outbuf)[oi] = f2bf(hn);
                    else    ((float*)outbuf)[oi] = hn;
                }
            }
        }
    }
}

// ---------------------------------------------------------------------------
extern "C" void kernel_launch(void* const* d_in, const int* in_sizes, int n_in,
                              void* d_out, int out_size, void* d_ws, size_t ws_size,
                              hipStream_t stream) {
    const void* states = d_in[0];
    const int*  edges  = (const int*)d_in[1];
    const void* type_W = d_in[2];
    const void* type_b = d_in[3];
    const void* gruk   = d_in[4];
    const void* grur   = d_in[5];
    const void* grub   = d_in[6];

    const int NN = in_sizes[0] / H;    // 50000
    const int NE = in_sizes[1] / 3;    // 400000
    const int nW = in_sizes[2];        // L*NT*128*128
    const int LAYERS = nW / (NT * H * H);

    // --- workspace layout ---
    char* w = (char*)d_ws;
    int* flag = (int*)w;                               w += 64;
    _Float16* h16A  = (_Float16*)w;                    w += (size_t)NN * H * 2;
    _Float16* h16B  = (_Float16*)w;                    w += (size_t)NN * H * 2;
    _Float16* A4    = (_Float16*)w;                    w += (size_t)NN * 4 * H * 2;
    _Float16* BTw = (_Float16*)w;                      w += (size_t)LAYERS * H * 512 * 2;
    _Float16* BTg = (_Float16*)w;                      w += (size_t)LAYERS * 512 * 256 * 2;
    float* btab  = (float*)w;                          w += (size_t)LAYERS * NT * H * 4;
    float* gbsum = (float*)w;                          w += (size_t)LAYERS * 256 * 4;
    float* gb0c  = (float*)w;                          w += (size_t)LAYERS * H * 4;
    float* gb1c  = (float*)w;                          w += (size_t)LAYERS * H * 4;
    int* counts4 = (int*)w;                            w += (size_t)NN * 4 * 4;
    int* buckets4 = (int*)w;                           // [NN][4][CAP4]

    detect_dtype<<<1, 256, 0, stream>>>((const unsigned short*)states, flag);

    const long NNH = (long)NN * H;
    const int nBTw = LAYERS * 65536;
    const int nBTg = LAYERS * 131072;
    const int NC4 = NN * 4;
    const long ptotal = NNH + nBTw + nBTg + NC4 + LAYERS * NT * H;
    prep_all<<<(int)((ptotal + 255) / 256), 256, 0, stream>>>(
        states, type_W, type_b, gruk, grur, grub,
        h16A, BTw, BTg, btab, gbsum, gb0c, gb1c, counts4, flag,
        NNH, nBTw, nBTg, NC4, LAYERS);

    place_edges4<<<(NE + 255) / 256, 256, 0, stream>>>(edges, counts4, buckets4, NE);

    const int rt64 = (NN + 63) / 64;
    for (int L = 0; L < LAYERS; L++) {
        const _Float16* hcur = (L & 1) ? h16B : h16A;
        _Float16* hnext      = (L & 1) ? h16A : h16B;

        gather4<<<(NN + 3) / 4, 256, 0, stream>>>(hcur, counts4, buckets4, A4, NN);

        layer_fused<<<rt64, 256, 0, stream>>>(
            A4, hcur,
            BTw + (size_t)L * H * 512,
            BTg + (size_t)L * 512 * 256,
            btab + (size_t)L * NT * H, (const int4*)counts4,
            gbsum + (size_t)L * 256, gb0c + (size_t)L * H, gb1c + (size_t)L * H,
            hnext, (L == LAYERS - 1) ? d_out : nullptr, flag, NN);
    }
}